// Round 5
// baseline (174.751 us; speedup 1.0000x reference)
//
#include <hip/hip_runtime.h>

typedef __attribute__((ext_vector_type(8))) short bf16x8;
typedef __attribute__((ext_vector_type(4))) float f32x4;
typedef __attribute__((ext_vector_type(4))) unsigned short u16x4;
typedef __attribute__((ext_vector_type(8))) unsigned short u16x8;

#define B_ 2048
#define A_ 50
#define H_ 512
#define NACT_ 64
#define F_ 562
#define BM_ 128
#define BK_ 64
#define NSTEP_ (H_ / BK_) /* 8 */

// ws layout (bytes)
#define WS_W1T 0
#define WS_W2T ((size_t)A_ * H_ * H_ * 2)                    /* 26,214,400 */
#define WS_B1 (WS_W2T + (size_t)A_ * NACT_ * H_ * 2)         /* 29,491,200 */
#define WS_B2 (WS_B1 + (size_t)A_ * H_ * 4)                  /* 29,593,600 */

static __device__ __forceinline__ unsigned short f2bf(float f) {
  unsigned int u = __builtin_bit_cast(unsigned int, f);
  u += 0x7fffu + ((u >> 16) & 1u);
  return (unsigned short)(u >> 16);
}

static __device__ __forceinline__ void gld_lds16(const unsigned short* src,
                                                 unsigned short* dst) {
  __builtin_amdgcn_global_load_lds(
      (const __attribute__((address_space(1))) unsigned int*)(const void*)src,
      (__attribute__((address_space(3))) unsigned int*)(void*)dst, 16, 0, 0);
}

static __device__ __forceinline__ int clamp_r(int r) {
  return r < 0 ? 0 : (r > A_ - 1 ? A_ - 1 : r);
}

// W1T slab layout for BK=64: slab t (k in [t*64,(t+1)*64)) is contiguous
// 64 KiB: [j 512][p 8][e 8] where chunk position p holds logical k-chunk
// c = p ^ (j&7)  (XOR involution -> conflict-free ds_read_b128).
__global__ void prep_w1(const float* __restrict__ w1,
                        const int* __restrict__ routing,
                        unsigned short* __restrict__ w1t) {
  const int bid = blockIdx.x;
  const int a = bid / 64;
  const int tile = bid - a * 64;
  const int tk = tile & 7, tj = tile >> 3; // tk = slab, tj = j-quarter
  const int k0 = tk * 64, j0 = tj * 64;
  const int r = clamp_r(routing[a]);
  __shared__ float tl[64][65];
  const int t = threadIdx.x;
  const int c = t & 63, q = t >> 6;
#pragma unroll
  for (int i = 0; i < 16; ++i) {
    const int kl = q + i * 4;
    tl[kl][c] = w1[((size_t)r * F_ + k0 + kl) * H_ + j0 + c];
  }
  __syncthreads();
  // thread t: jl = t>>2, c2 = t&3; chunk-pos p = it*4+c2 holds c = p^(jl&7)
#pragma unroll
  for (int it = 0; it < 2; ++it) {
    const int jl = t >> 2, c2 = t & 3;
    const int p = it * 4 + c2;
    const int cl = p ^ (jl & 7);
    u16x8 v;
#pragma unroll
    for (int e = 0; e < 8; ++e) v[e] = f2bf(tl[cl * 8 + e][jl]);
    unsigned short* dst =
        w1t + (((size_t)a * 8 + tk) * H_ + j0 + jl) * 64 + p * 8;
    *(u16x8*)dst = v;
  }
}

// W2T[a][n][k] = bf16(W2[r_a][k][n])
__global__ void prep_w2(const float* __restrict__ w2,
                        const int* __restrict__ routing,
                        unsigned short* __restrict__ w2t) {
  const int bid = blockIdx.x;
  const int a = bid >> 3;
  const int tk = bid & 7;
  const int k0 = tk * 64;
  const int r = clamp_r(routing[a]);
  __shared__ float tl[64][65];
  const int t = threadIdx.x;
  const int c = t & 63, q = t >> 6;
#pragma unroll
  for (int i = 0; i < 16; ++i) {
    const int kl = q + i * 4;
    tl[kl][c] = w2[((size_t)r * H_ + k0 + kl) * NACT_ + c];
  }
  __syncthreads();
#pragma unroll
  for (int i = 0; i < 16; ++i) {
    const int nl = q + i * 4;
    w2t[((size_t)a * NACT_ + nl) * H_ + k0 + c] = f2bf(tl[c][nl]);
  }
}

__global__ void prep_bias(const float* __restrict__ w1,
                          const float* __restrict__ b1,
                          const float* __restrict__ b2,
                          const int* __restrict__ routing,
                          float* __restrict__ bias1, float* __restrict__ bias2) {
  const int a = blockIdx.x;
  const int t = threadIdx.x;
  const int r = clamp_r(routing[a]);
  bias1[a * H_ + t] = b1[(size_t)r * H_ + t] + w1[((size_t)r * F_ + H_ + a) * H_ + t];
  if (t < NACT_) bias2[a * NACT_ + t] = b2[r * NACT_ + t];
}

__global__ __launch_bounds__(512, 2) void divtree_main(
    const float* __restrict__ x, const unsigned short* __restrict__ w1t,
    const unsigned short* __restrict__ w2t, const float* __restrict__ bias1,
    const float* __restrict__ bias2, float* __restrict__ out) {
  __shared__ union {
    struct {
      unsigned short w1[2][H_ * BK_]; // 2 x 64 KiB, linear (pre-swizzled)
      unsigned short xs[BM_ * BK_];   // 16 KiB, single buffer (bar2-guarded)
    } st;                             // 144 KiB
    unsigned short h[BM_ * H_];       // 128 KiB (after K-loop)
    float outb[BM_][66];              // 33 KiB (after layer 2)
  } sm;

  // XCD-bijective swizzle: 800 blocks, 800 % 8 == 0 -> cpx = 100
  const int bid = blockIdx.x;
  const int swz = (bid & 7) * 100 + (bid >> 3);
  const int a = swz >> 4;    // agent (0..49)
  const int mblk = swz & 15; // M tile (0..15)
  const int b0 = mblk * BM_;

  const int tid = threadIdx.x;
  const int lane = tid & 63;
  const int w = tid >> 6; // wave 0..7
  const int l16 = lane & 15;
  const int lk = lane >> 4;       // 0..3
  const int l7 = l16 & 7;         // row&7 for all fragment rows

  // L1 wave tile: 128(j) x 64(m): wnq = j-quad (0..3), wm = m-half (0..1)
  const int wnq = w & 3;
  const int wm = w >> 2;

  const unsigned short* w1ta = w1t + (size_t)a * (H_ * H_);

  // x staging: thread -> row = tid>>2 (0..127), seg = tid&3 (16 floats)
  const int xrow = tid >> 2;
  const int xseg = tid & 3;
  const float* xbase =
      x + ((size_t)(b0 + xrow) * A_ + (size_t)a) * H_ + (size_t)xseg * 16;
  // xs write chunk positions: c = xseg*2 + {0,1}, p = c ^ (xrow&7)
  const int xp0 = (xseg * 2) ^ (xrow & 7);
  const int xp1 = (xseg * 2 + 1) ^ (xrow & 7);
  unsigned short* xs0 = sm.st.xs + xrow * BK_;

  f32x4 acc[8][4];
#pragma unroll
  for (int i = 0; i < 8; ++i)
#pragma unroll
    for (int j = 0; j < 4; ++j) acc[i][j] = (f32x4){0.f, 0.f, 0.f, 0.f};

  f32x4 xr[2][4]; // x(t) in slot t&1; static indices via full unroll

  // ---- prologue ----
  {
    f32x4 x0[4];
#pragma unroll
    for (int i = 0; i < 4; ++i) x0[i] = *(const f32x4*)(xbase + i * 4);
#pragma unroll
    for (int i = 0; i < 8; ++i)
      gld_lds16(w1ta + ((size_t)(i * 512 + tid) << 3),
                sm.st.w1[0] + (size_t)(i * 512 + (w << 6)) * 8);
    u16x8 v0, v1;
#pragma unroll
    for (int e = 0; e < 4; ++e) {
      v0[e] = f2bf(x0[0][e]); v0[4 + e] = f2bf(x0[1][e]);
      v1[e] = f2bf(x0[2][e]); v1[4 + e] = f2bf(x0[3][e]);
    }
    *(u16x8*)(xs0 + xp0 * 8) = v0;
    *(u16x8*)(xs0 + xp1 * 8) = v1;
#pragma unroll
    for (int i = 0; i < 4; ++i)
      xr[1][i] = *(const f32x4*)(xbase + 1 * BK_ + i * 4);
    asm volatile("s_waitcnt vmcnt(4) lgkmcnt(0)" ::: "memory");
    __builtin_amdgcn_sched_barrier(0);
    __builtin_amdgcn_s_barrier();
    __builtin_amdgcn_sched_barrier(0);
  }

  // ---- K-loop: fat phases, counted vmcnt, never 0 until tail ----
#pragma unroll
  for (int t = 0; t < NSTEP_; ++t) {
    const int buf = t & 1;
    // (A) issue W1 stage for t+1 (waited at (G) -> full-iter cover)
    if (t + 1 < NSTEP_) {
      const unsigned short* wsrc = w1ta + (size_t)(t + 1) * (H_ * BK_);
      unsigned short* wdst = sm.st.w1[buf ^ 1];
#pragma unroll
      for (int i = 0; i < 8; ++i)
        gld_lds16(wsrc + ((size_t)(i * 512 + tid) << 3),
                  wdst + (size_t)(i * 512 + (w << 6)) * 8);
    }
    const unsigned short* w1s = sm.st.w1[buf];
    // (B) kh0: frag reads + 32 MFMA
    {
      bf16x8 afr[8], bfr[4];
#pragma unroll
      for (int jf = 0; jf < 8; ++jf)
        afr[jf] = *(const bf16x8*)(w1s + (wnq * 128 + jf * 16 + l16) * 64 +
                                   ((0 * 4 + lk) ^ l7) * 8);
#pragma unroll
      for (int mf = 0; mf < 4; ++mf)
        bfr[mf] = *(const bf16x8*)(sm.st.xs + (wm * 64 + mf * 16 + l16) * 64 +
                                   ((0 * 4 + lk) ^ l7) * 8);
      __builtin_amdgcn_s_setprio(1);
#pragma unroll
      for (int jf = 0; jf < 8; ++jf)
#pragma unroll
        for (int mf = 0; mf < 4; ++mf)
          acc[jf][mf] = __builtin_amdgcn_mfma_f32_16x16x32_bf16(
              afr[jf], bfr[mf], acc[jf][mf], 0, 0, 0);
      __builtin_amdgcn_s_setprio(0);
    }
    // (C) kh1 frag reads; bar2 (all xs/w1 reads of iter t complete)
    {
      bf16x8 afr[8], bfr[4];
#pragma unroll
      for (int jf = 0; jf < 8; ++jf)
        afr[jf] = *(const bf16x8*)(w1s + (wnq * 128 + jf * 16 + l16) * 64 +
                                   ((1 * 4 + lk) ^ l7) * 8);
#pragma unroll
      for (int mf = 0; mf < 4; ++mf)
        bfr[mf] = *(const bf16x8*)(sm.st.xs + (wm * 64 + mf * 16 + l16) * 64 +
                                   ((1 * 4 + lk) ^ l7) * 8);
      asm volatile("s_waitcnt lgkmcnt(0)" ::: "memory");
      __builtin_amdgcn_sched_barrier(0);
      __builtin_amdgcn_s_barrier(); // bar2: xs now writable
      // (D) kh1 MFMA
      __builtin_amdgcn_s_setprio(1);
#pragma unroll
      for (int jf = 0; jf < 8; ++jf)
#pragma unroll
        for (int mf = 0; mf < 4; ++mf)
          acc[jf][mf] = __builtin_amdgcn_mfma_f32_16x16x32_bf16(
              afr[jf], bfr[mf], acc[jf][mf], 0, 0, 0);
      __builtin_amdgcn_s_setprio(0);
    }
    // (E) x(t+1) arrived (issued a full iter ago): cvt + xs write
    if (t + 1 < NSTEP_) {
      asm volatile("s_waitcnt vmcnt(8)" ::: "memory"); // leave 8 W1 glds
      __builtin_amdgcn_sched_barrier(0);
      u16x8 v0, v1;
#pragma unroll
      for (int e = 0; e < 4; ++e) {
        v0[e] = f2bf(xr[(t + 1) & 1][0][e]);
        v0[4 + e] = f2bf(xr[(t + 1) & 1][1][e]);
        v1[e] = f2bf(xr[(t + 1) & 1][2][e]);
        v1[4 + e] = f2bf(xr[(t + 1) & 1][3][e]);
      }
      *(u16x8*)(xs0 + xp0 * 8) = v0;
      *(u16x8*)(xs0 + xp1 * 8) = v1;
    }
    // (F) issue x(t+2)
    if (t + 2 < NSTEP_) {
#pragma unroll
      for (int i = 0; i < 4; ++i)
        xr[t & 1][i] = *(const f32x4*)(xbase + (size_t)(t + 2) * BK_ + i * 4);
    }
    // (G) end: drain W1 glds (t+1), keep x(t+2) in flight; publish barrier
    if (t + 2 < NSTEP_)
      asm volatile("s_waitcnt vmcnt(4) lgkmcnt(0)" ::: "memory");
    else
      asm volatile("s_waitcnt vmcnt(0) lgkmcnt(0)" ::: "memory");
    __builtin_amdgcn_sched_barrier(0);
    __builtin_amdgcn_s_barrier();
    __builtin_amdgcn_sched_barrier(0);
  }

  // ---- h = relu(acc + bias1_eff) -> LDS bf16, XOR-swizzled ----
  const float* b1p = bias1 + a * H_;
#pragma unroll
  for (int jf = 0; jf < 8; ++jf) {
    const f32x4 bv = *(const f32x4*)(b1p + wnq * 128 + jf * 16 + lk * 4);
    const int cJ = wnq * 16 + jf * 2 + (lk >> 1);
    const int half4 = (lk & 1) * 4;
#pragma unroll
    for (int mf = 0; mf < 4; ++mf) {
      u16x4 hv;
#pragma unroll
      for (int r = 0; r < 4; ++r) {
        float f = acc[jf][mf][r] + bv[r];
        f = f > 0.f ? f : 0.f;
        hv[r] = f2bf(f);
      }
      const int m = wm * 64 + mf * 16 + l16;
      const int off = m * H_ + ((cJ ^ (m & 7))) * 8 + half4;
      *(u16x4*)(sm.h + off) = hv;
    }
  }
  __syncthreads();

  // ---- layer 2: wave tile 32(m) x 32(n); mq = w>>1, nh = w&1 ----
  const int m0 = (w >> 1) * 32;
  const int n0 = (w & 1) * 32;
  f32x4 acc2[2][2];
#pragma unroll
  for (int i = 0; i < 2; ++i)
#pragma unroll
    for (int j = 0; j < 2; ++j) acc2[i][j] = (f32x4){0.f, 0.f, 0.f, 0.f};
#pragma unroll
  for (int kf = 0; kf < 16; ++kf) {
    bf16x8 bf2[2], af2[2];
#pragma unroll
    for (int nf = 0; nf < 2; ++nf)
      bf2[nf] = *(const bf16x8*)(w2t +
                                 ((size_t)a * NACT_ + n0 + nf * 16 + l16) * H_ +
                                 kf * 32 + lk * 8);
#pragma unroll
    for (int mf = 0; mf < 2; ++mf) {
      const int row = m0 + mf * 16 + l16;
      af2[mf] = *(const bf16x8*)(sm.h + row * H_ +
                                 (((kf * 4 + lk) ^ (l16 & 7))) * 8);
    }
#pragma unroll
    for (int mf = 0; mf < 2; ++mf)
#pragma unroll
      for (int nf = 0; nf < 2; ++nf)
        acc2[mf][nf] = __builtin_amdgcn_mfma_f32_16x16x32_bf16(
            af2[mf], bf2[nf], acc2[mf][nf], 0, 0, 0);
  }
  float b2v[2];
#pragma unroll
  for (int nf = 0; nf < 2; ++nf)
    b2v[nf] = bias2[a * NACT_ + n0 + nf * 16 + l16];
  __syncthreads(); // all h reads done before outb overwrite (aliased)
#pragma unroll
  for (int mf = 0; mf < 2; ++mf)
#pragma unroll
    for (int nf = 0; nf < 2; ++nf)
#pragma unroll
      for (int r = 0; r < 4; ++r)
        sm.outb[m0 + mf * 16 + lk * 4 + r][n0 + nf * 16 + l16] =
            acc2[mf][nf][r] + b2v[nf];
  __syncthreads();

  // coalesced out store: 256B contiguous per row
  {
    const int row = tid >> 2;
    const int sg = (tid & 3) * 16;
    float* op = out + ((size_t)(b0 + row) * A_ + a) * NACT_ + sg;
#pragma unroll
    for (int i = 0; i < 4; ++i)
      *(f32x4*)(op + i * 4) = *(const f32x4*)(&sm.outb[row][sg + i * 4]);
  }
}

extern "C" void kernel_launch(void* const* d_in, const int* in_sizes, int n_in,
                              void* d_out, int out_size, void* d_ws,
                              size_t ws_size, hipStream_t stream) {
  const float* x = (const float*)d_in[0];
  const float* w1 = (const float*)d_in[1];
  const float* b1 = (const float*)d_in[2];
  const float* w2 = (const float*)d_in[3];
  const float* b2 = (const float*)d_in[4];
  const int* routing = (const int*)d_in[5];
  float* out = (float*)d_out;

  char* ws = (char*)d_ws;
  unsigned short* w1t = (unsigned short*)(ws + WS_W1T);
  unsigned short* w2t = (unsigned short*)(ws + WS_W2T);
  float* bias1 = (float*)(ws + WS_B1);
  float* bias2 = (float*)(ws + WS_B2);

  prep_w1<<<A_ * 64, 256, 0, stream>>>(w1, routing, w1t);
  prep_w2<<<A_ * 8, 256, 0, stream>>>(w2, routing, w2t);
  prep_bias<<<A_, 512, 0, stream>>>(w1, b1, b2, routing, bias1, bias2);
  divtree_main<<<A_ * (B_ / BM_), 512, 0, stream>>>(x, w1t, w2t, bias1, bias2,
                                                    out);
}